// Round 17
// baseline (174.487 us; speedup 1.0000x reference)
//
#include <hip/hip_runtime.h>
#include <hip/hip_bf16.h>
#include <stdint.h>

#define Bb 2
#define Ss 2048
#define Dd 1024
#define Hh 16
#define DKk 64

// softmax scale folded into Q at projection time: 1/sqrt(64) * log2(e)
#define QSCALE 0.180336878f

typedef __attribute__((ext_vector_type(8))) short s8v;
typedef __attribute__((ext_vector_type(4))) short s4v;
typedef __attribute__((ext_vector_type(4))) float f4v;
typedef __attribute__((ext_vector_type(16))) float f16v;

#if __has_builtin(__builtin_amdgcn_exp2f)
#define EXP2(x) __builtin_amdgcn_exp2f(x)
#else
#define EXP2(x) __expf((x)*0.69314718f)
#endif

__device__ __forceinline__ unsigned short f2bf(float f) {
    __hip_bfloat16 h = __float2bfloat16(f);
    union { __hip_bfloat16 h; unsigned short u; } c; c.h = h;
    return c.u;
}

__device__ __forceinline__ unsigned pack_bf2(float lo, float hi) {
    __hip_bfloat162 h = __float22bfloat162_rn(float2{lo, hi});
    union { __hip_bfloat162 h; unsigned u; } c; c.h = h;
    return c.u;
}

__device__ __forceinline__ void gload16(const void* g, void* l) {
    __builtin_amdgcn_global_load_lds((__attribute__((address_space(1))) void*)g,
                                     (__attribute__((address_space(3))) void*)l, 16, 0, 0);
}

// ---------------- prep: transpose+convert weights to [n][k] bf16 ----------------
__global__ void __launch_bounds__(256) prep_w(const float* __restrict__ Wq,
                                              const float* __restrict__ Wk,
                                              const float* __restrict__ Wv,
                                              const float* __restrict__ Wo,
                                              unsigned short* __restrict__ o0,
                                              unsigned short* __restrict__ o1,
                                              unsigned short* __restrict__ o2,
                                              unsigned short* __restrict__ o3) {
    __shared__ float t[64][65];
    const int z = blockIdx.z;
    const float* W = (z == 0) ? Wq : ((z == 1) ? Wk : ((z == 2) ? Wv : Wo));
    unsigned short* O = (z == 0) ? o0 : ((z == 1) ? o1 : ((z == 2) ? o2 : o3));
    const int n0 = (blockIdx.x & 15) * 64;
    const int k0 = (blockIdx.x >> 4) * 64;
    const int c = threadIdx.x & 63;
    const int r4 = threadIdx.x >> 6;
#pragma unroll
    for (int i = 0; i < 16; i++) {
        int r = i * 4 + r4;
        t[r][c] = W[(long)(k0 + r) * Dd + n0 + c];
    }
    __syncthreads();
#pragma unroll
    for (int i = 0; i < 16; i++) {
        int r = i * 4 + r4;  // n-local
        O[(long)(n0 + r) * Dd + k0 + c] = f2bf(t[c][r]);
    }
}

// ---------------- GEMM body: R15-validated 2-phase K-loop ----------------
// MODE 0: bf16 head-split [B,H,S,DK] (scaled); MODE 1: bf16 [B,H,DK,S]; MODE 2: f32.
// AF32: A is f32 in global, staged AS F32 via async global_load_lds (slot =
// gd^(row&15), R14-validated addressing); converted to bf16 during the phase-2
// register reads (where R15 proved latency hides). Else: validated bf16 path.
template <int MODE, bool AF32>
__device__ __forceinline__ void gemm_body(const void* __restrict__ Av,
                                          const unsigned short* __restrict__ Bt,
                                          const float* __restrict__ bias,
                                          void* __restrict__ out, float oscale,
                                          char* smem, int m0, int n0) {
    char* As = smem;                              // AF32: 32KB f32 / else 16KB bf16
    char* Bs = smem + (AF32 ? 32768 : 16384);     // 16KB bf16
    const int tid = threadIdx.x;
    const int l = tid & 63;
    const int w = tid >> 6;
    const int wr = w >> 1, wc = w & 1;
    const int lr = l & 15, lg = l >> 4;

    f4v acc[4][4];
#pragma unroll
    for (int m = 0; m < 4; m++)
#pragma unroll
        for (int n = 0; n < 4; n++) acc[m][n] = (f4v){0.f, 0.f, 0.f, 0.f};

    const int srow = tid >> 3;              // 0..31 (row within 32-row chunk)
    const int sg = (tid & 7) ^ (srow & 7);  // pre-swizzled source granule (T2 both-sides)
    char* lbaseB = Bs + w * 1024;

#define STAGE_T(t_)                                                                     \
    do {                                                                                \
        const int k0_ = (t_) * 64;                                                      \
        if (AF32) {                                                                     \
            const float* A32_ = (const float*)Av;                                       \
            _Pragma("unroll") for (int i_ = 0; i_ < 8; i_++) {                          \
                const int G0_ = i_ * 256 + w * 64;                                      \
                int G_ = G0_ + l;                                                       \
                int row_ = G_ >> 4, gd_ = G_ & 15;                                      \
                int gs_ = gd_ ^ (row_ & 15);                                            \
                gload16(A32_ + (long)(m0 + row_) * 1024 + k0_ + gs_ * 4,                \
                        As + G0_ * 16);                                                 \
            }                                                                           \
        } else {                                                                        \
            const unsigned short* A_ = (const unsigned short*)Av;                       \
            char* lbaseA_ = As + w * 1024;                                              \
            _Pragma("unroll") for (int i_ = 0; i_ < 4; i_++) {                          \
                int rowA_ = i_ * 32 + srow;                                             \
                gload16((const char*)A_ + ((long)(m0 + rowA_) * 1024 + k0_) * 2 +       \
                            sg * 16,                                                    \
                        lbaseA_ + i_ * 4096);                                           \
            }                                                                           \
        }                                                                               \
        _Pragma("unroll") for (int i_ = 0; i_ < 4; i_++) {                              \
            int rowA_ = i_ * 32 + srow;                                                 \
            gload16((const char*)Bt + ((long)(n0 + rowA_) * 1024 + k0_) * 2 + sg * 16,  \
                    lbaseB + i_ * 4096);                                                \
        }                                                                               \
    } while (0)

    STAGE_T(0);
    for (int t = 0; t < 16; t++) {
        asm volatile("s_waitcnt vmcnt(0)" ::: "memory");
        __builtin_amdgcn_s_barrier();       // LDS tile t ready (all waves)
        __builtin_amdgcn_sched_barrier(0);

        // read ALL fragments for this tile into registers (AF32: convert here)
        s8v af[2][4], bfr[2][4];
#pragma unroll
        for (int kk = 0; kk < 2; kk++) {
#pragma unroll
            for (int m = 0; m < 4; m++) {
                int row = wr * 64 + m * 16 + lr;
                if (AF32) {
                    int g0 = kk * 8 + lg * 2;       // f32 granule pair (R14-validated)
                    int s0 = g0 ^ (row & 15);
                    f4v a0 = *(const f4v*)(As + (row * 16 + s0) * 16);
                    f4v a1 = *(const f4v*)(As + (row * 16 + (s0 ^ 1)) * 16);
                    union { unsigned u[4]; s8v v; } o;
                    o.u[0] = pack_bf2(a0[0], a0[1]);
                    o.u[1] = pack_bf2(a0[2], a0[3]);
                    o.u[2] = pack_bf2(a1[0], a1[1]);
                    o.u[3] = pack_bf2(a1[2], a1[3]);
                    af[kk][m] = o.v;
                } else {
                    int gc = (kk * 4 + lg) ^ (row & 7);
                    af[kk][m] = *(const s8v*)(As + row * 128 + gc * 16);
                }
            }
#pragma unroll
            for (int n = 0; n < 4; n++) {
                int row = wc * 64 + n * 16 + lr;
                int gc = (kk * 4 + lg) ^ (row & 7);
                bfr[kk][n] = *(const s8v*)(Bs + row * 128 + gc * 16);
            }
        }
        asm volatile("s_waitcnt lgkmcnt(0)" ::: "memory");
        __builtin_amdgcn_sched_barrier(0);  // rule #18: fence reads before barrier
        __builtin_amdgcn_s_barrier();       // all waves done reading LDS tile t
        __builtin_amdgcn_sched_barrier(0);

        if (t + 1 < 16) STAGE_T(t + 1);     // async overwrite; hidden under MFMAs

#pragma unroll
        for (int kk = 0; kk < 2; kk++)
#pragma unroll
            for (int m = 0; m < 4; m++)
#pragma unroll
                for (int n = 0; n < 4; n++)
                    acc[m][n] = __builtin_amdgcn_mfma_f32_16x16x32_bf16(
                        af[kk][m], bfr[kk][n], acc[m][n], 0, 0, 0);
    }
#undef STAGE_T

#pragma unroll
    for (int n = 0; n < 4; n++) {
        int col = n0 + wc * 64 + n * 16 + lr;
        float bv = bias[col];
#pragma unroll
        for (int m = 0; m < 4; m++) {
#pragma unroll
            for (int r = 0; r < 4; r++) {
                int row = m0 + wr * 64 + m * 16 + lg * 4 + r;
                float val = acc[m][n][r] + bv;
                if (MODE == 0) {
                    int b = row >> 11, s2 = row & 2047, h = col >> 6, d = col & 63;
                    ((unsigned short*)out)[(((b * Hh + h) * Ss + s2) << 6) + d] =
                        f2bf(val * oscale);
                } else if (MODE == 1) {
                    int b = row >> 11, s2 = row & 2047, h = col >> 6, d = col & 63;
                    ((unsigned short*)out)[((b * Hh + h) * DKk + d) * Ss + s2] = f2bf(val);
                } else {
                    ((float*)out)[(long)row * Dd + col] = val;
                }
            }
        }
    }
}

// T1 bijective XCD swizzle for a 256-block slice (256 % 8 == 0).
__device__ __forceinline__ void xcd_tile(int bid, int& m0, int& n0) {
    int content = (bid & 7) * 32 + (bid >> 3);
    n0 = (content & 7) * 128;
    m0 = (content >> 3) * 128;
}

__global__ void __launch_bounds__(256) qkv_gemm(const float* __restrict__ q,
                                                const float* __restrict__ k,
                                                const float* __restrict__ v,
                                                const unsigned short* __restrict__ Wqt,
                                                const unsigned short* __restrict__ Wkt,
                                                const unsigned short* __restrict__ Wvt,
                                                const float* __restrict__ bq,
                                                const float* __restrict__ bk,
                                                const float* __restrict__ bv,
                                                unsigned short* __restrict__ Qh,
                                                unsigned short* __restrict__ Kh,
                                                unsigned short* __restrict__ Vt) {
    __shared__ __align__(16) char smem[49152];  // A f32 32KB + B bf16 16KB
    int m0, n0;
    xcd_tile(blockIdx.x, m0, n0);
    const int z = blockIdx.z;
    if (z == 0)
        gemm_body<0, true>(q, Wqt, bq, Qh, QSCALE, smem, m0, n0);
    else if (z == 1)
        gemm_body<0, true>(k, Wkt, bk, Kh, 1.f, smem, m0, n0);
    else
        gemm_body<1, true>(v, Wvt, bv, Vt, 1.f, smem, m0, n0);
}

__global__ void __launch_bounds__(256) out_gemm(const unsigned short* __restrict__ x,
                                                const unsigned short* __restrict__ Wot,
                                                const float* __restrict__ bo,
                                                float* __restrict__ out) {
    __shared__ __align__(16) char smem[32768];
    int m0, n0;
    xcd_tile(blockIdx.x, m0, n0);
    gemm_body<2, false>(x, Wot, bo, out, 1.f, smem, m0, n0);
}

// ---------------- flash attention (R16-validated: 2-phase chunk loop, 67.0 us) ----
__global__ void __launch_bounds__(256) attn_kernel(const unsigned short* __restrict__ Qh,
                                                   const unsigned short* __restrict__ Kh,
                                                   const unsigned short* __restrict__ Vt,
                                                   unsigned short* __restrict__ xatt) {
    __shared__ __align__(16) char ldsbuf[32768];
    unsigned short* Ks = (unsigned short*)ldsbuf;            // 16 KB: [128 rows][8 gran]
    unsigned short* Vs = (unsigned short*)(ldsbuf + 16384);  // 16 KB: [64 rows][16 gran]
    const int tid = threadIdx.x;
    const int w = tid >> 6, l = tid & 63;
    const int lq = l & 31;   // operand row index / q column
    const int hi = l >> 5;   // half-lane group
    const int bh = blockIdx.x & 31;          // b*16+h
    const int tile = 63 - (blockIdx.x >> 5); // longest-running tiles dispatch first
    const int q0 = tile * 32;
    const int b = bh >> 4, h = bh & 15;
    const unsigned short* Qp = Qh + bh * Ss * DKk;
    const unsigned short* Kp = Kh + bh * Ss * DKk;
    const unsigned short* Vp = Vt + bh * DKk * Ss;

    // Q as B-operand: row = q (lane&31), k = kk*16 + hi*8 + j
    s8v qf[4];
#pragma unroll
    for (int kk = 0; kk < 4; kk++)
        qf[kk] = *(const s8v*)(Qp + (q0 + lq) * 64 + kk * 16 + hi * 8);

    f16v oT0, oT1;
#pragma unroll
    for (int r = 0; r < 16; r++) { oT0[r] = 0.f; oT1[r] = 0.f; }
    float mx = -1e30f, sm = 0.f;
    const int nkb = tile + 1;          // 32-kv sub-blocks
    const int nch = (nkb + 3) >> 2;    // 128-kv chunks

#define STAGE_CH(ch_)                                                          \
    do {                                                                       \
        const int kv0_ = (ch_) * 128;                                          \
        _Pragma("unroll") for (int i_ = 0; i_ < 4; i_++) {                     \
            const int G0_ = i_ * 256 + w * 64;                                 \
            int G_ = G0_ + l;                                                  \
            int row_ = G_ >> 3, gd_ = G_ & 7;                                  \
            int gs_ = gd_ ^ (row_ & 7);                                        \
            gload16(Kp + (kv0_ + row_) * 64 + gs_ * 8, (char*)Ks + G0_ * 16);  \
        }                                                                      \
        _Pragma("unroll") for (int i_ = 0; i_ < 4; i_++) {                     \
            const int G0_ = i_ * 256 + w * 64;                                 \
            int G_ = G0_ + l;                                                  \
            int row_ = G_ >> 4, gd_ = G_ & 15;                                 \
            int gs_ = gd_ ^ (row_ & 15);                                       \
            gload16(Vp + (long)row_ * Ss + kv0_ + gs_ * 8, (char*)Vs + G0_ * 16); \
        }                                                                      \
    } while (0)

    STAGE_CH(0);
    for (int ch = 0; ch < nch; ch++) {
        asm volatile("s_waitcnt vmcnt(0)" ::: "memory");
        __builtin_amdgcn_s_barrier();       // chunk ch staged (all waves)
        __builtin_amdgcn_sched_barrier(0);

        // read ALL K/V fragments to registers (unconditional; addresses always valid)
        s8v kf[4], vf0[2], vf1[2];
#pragma unroll
        for (int kk = 0; kk < 4; kk++) {
            int row = w * 32 + lq;
            int g = (2 * kk + hi) ^ (row & 7);
            kf[kk] = *(const s8v*)((const char*)Ks + (row * 8 + g) * 16);
        }
#pragma unroll
        for (int kk = 0; kk < 2; kk++) {
            int g0 = 4 * w + 2 * kk + hi;
            vf0[kk] = *(const s8v*)((const char*)Vs + (lq * 16 + (g0 ^ (lq & 15))) * 16);
            vf1[kk] =
                *(const s8v*)((const char*)Vs + ((32 + lq) * 16 + (g0 ^ (lq & 15))) * 16);
        }
        asm volatile("s_waitcnt lgkmcnt(0)" ::: "memory");
        __builtin_amdgcn_sched_barrier(0);  // rule #18: fence reads before barrier
        __builtin_amdgcn_s_barrier();       // all waves done reading chunk ch
        __builtin_amdgcn_sched_barrier(0);

        if (ch + 1 < nch) STAGE_CH(ch + 1); // async overwrite; hidden under compute

        const int kb = ch * 4 + w;  // my 32-kv sub-block
        if (kb < nkb) {
            const int k0 = kb * 32;
            f16v S;
#pragma unroll
            for (int r = 0; r < 16; r++) S[r] = 0.f;
#pragma unroll
            for (int kk = 0; kk < 4; kk++)
                S = __builtin_amdgcn_mfma_f32_32x32x16_bf16(kf[kk], qf[kk], S, 0, 0, 0);

            const bool diag = (kb == nkb - 1);
            float e[16];
#pragma unroll
            for (int r = 0; r < 16; r++) {
                float v = S[r];
                if (diag) {
                    int kv = k0 + (r & 3) + 8 * (r >> 2) + 4 * hi;
                    if (kv > q0 + lq) v = -1e30f;
                }
                e[r] = v;
            }
            // tree max (depth 4) + cross-half via shfl_xor (validated)
            float m8[8];
#pragma unroll
            for (int i = 0; i < 8; i++) m8[i] = fmaxf(e[i], e[i + 8]);
#pragma unroll
            for (int i = 0; i < 4; i++) m8[i] = fmaxf(m8[i], m8[i + 4]);
            float pmax = fmaxf(fmaxf(m8[0], m8[1]), fmaxf(m8[2], m8[3]));
            pmax = fmaxf(pmax, __shfl_xor(pmax, 32));

            if (!__all(pmax - mx <= 8.f)) {
                float mn = fmaxf(mx, pmax);
                float sc = EXP2(mx - mn);
                mx = mn;
                sm *= sc;
#pragma unroll
                for (int r = 0; r < 16; r++) { oT0[r] *= sc; oT1[r] *= sc; }
            }
#pragma unroll
            for (int r = 0; r < 16; r++) e[r] = EXP2(e[r] - mx);
            float s8s[8];
#pragma unroll
            for (int i = 0; i < 8; i++) s8s[i] = e[i] + e[i + 8];
#pragma unroll
            for (int i = 0; i < 4; i++) s8s[i] = s8s[i] + s8s[i + 4];
            float rs = (s8s[0] + s8s[1]) + (s8s[2] + s8s[3]);
            sm += rs + __shfl_xor(rs, 32);

            // pack P to bf16x2 pairs; half-exchange via shfl_xor (R5-validated mapping)
            unsigned pk[8], sw[8];
#pragma unroll
            for (int i = 0; i < 8; i++) pk[i] = pack_bf2(e[2 * i], e[2 * i + 1]);
#pragma unroll
            for (int i = 0; i < 8; i++) sw[i] = (unsigned)__shfl_xor((int)pk[i], 32);
            union { unsigned u[4]; s8v v; } p0, p1;
            p0.u[0] = hi ? sw[2] : pk[0];
            p0.u[1] = hi ? sw[3] : pk[1];
            p0.u[2] = hi ? pk[2] : sw[0];
            p0.u[3] = hi ? pk[3] : sw[1];
            p1.u[0] = hi ? sw[6] : pk[4];
            p1.u[1] = hi ? sw[7] : pk[5];
            p1.u[2] = hi ? pk[6] : sw[4];
            p1.u[3] = hi ? pk[7] : sw[5];

            oT0 = __builtin_amdgcn_mfma_f32_32x32x16_bf16(vf0[0], p0.v, oT0, 0, 0, 0);
            oT0 = __builtin_amdgcn_mfma_f32_32x32x16_bf16(vf0[1], p1.v, oT0, 0, 0, 0);
            oT1 = __builtin_amdgcn_mfma_f32_32x32x16_bf16(vf1[0], p0.v, oT1, 0, 0, 0);
            oT1 = __builtin_amdgcn_mfma_f32_32x32x16_bf16(vf1[1], p1.v, oT1, 0, 0, 0);
        }
    }
#undef STAGE_CH

    // ---- merge the 4 per-wave partials (2-round LDS tree; aliases staging LDS).
    // Safe: final iteration's vmcnt(0) retired all staging; compute is register-only.
    float(*plds)[64][34] = (float(*)[64][34])ldsbuf;
    if (w >= 2) {
        float* p = plds[w - 2][l];
        p[0] = mx; p[1] = sm;
#pragma unroll
        for (int r = 0; r < 16; r++) { p[2 + r] = oT0[r]; p[18 + r] = oT1[r]; }
    }
    __syncthreads();
    if (w < 2) {
        const float* p = plds[w][l];
        float m2 = p[0], s2 = p[1];
        float M = fmaxf(mx, m2);
        float a = EXP2(mx - M), bb = EXP2(m2 - M);
        sm = sm * a + s2 * bb;
#pragma unroll
        for (int r = 0; r < 16; r++) {
            oT0[r] = oT0[r] * a + p[2 + r] * bb;
            oT1[r] = oT1[r] * a + p[18 + r] * bb;
        }
        mx = M;
    }
    __syncthreads();
    if (w == 1) {
        float* p = plds[0][l];
        p[0] = mx; p[1] = sm;
#pragma unroll
        for (int r = 0; r < 16; r++) { p[2 + r] = oT0[r]; p[18 + r] = oT1[r]; }
    }
    __syncthreads();
    if (w != 0) return;
    {
        const float* p = plds[0][l];
        float m2 = p[0], s2 = p[1];
        float M = fmaxf(mx, m2);
        float a = EXP2(mx - M), bb = EXP2(m2 - M);
        sm = sm * a + s2 * bb;
#pragma unroll
        for (int r = 0; r < 16; r++) {
            oT0[r] = oT0[r] * a + p[2 + r] * bb;
            oT1[r] = oT1[r] * a + p[18 + r] * bb;
        }
    }

    // epilogue: O^T col = q (lane-local), row d = (r&3)+8*(r>>2)+4*hi
    const float inv = 1.f / sm;
    const int q = q0 + lq;
    unsigned short* orow = xatt + (long)(b * Ss + q) * Dd + h * 64;
#pragma unroll
    for (int g = 0; g < 4; g++) {
        union { unsigned u[2]; s4v v; } v0, v1;
        v0.u[0] = pack_bf2(oT0[g * 4 + 0] * inv, oT0[g * 4 + 1] * inv);
        v0.u[1] = pack_bf2(oT0[g * 4 + 2] * inv, oT0[g * 4 + 3] * inv);
        v1.u[0] = pack_bf2(oT1[g * 4 + 0] * inv, oT1[g * 4 + 1] * inv);
        v1.u[1] = pack_bf2(oT1[g * 4 + 2] * inv, oT1[g * 4 + 3] * inv);
        int d = 8 * g + 4 * hi;
        *(s4v*)(orow + d) = v0.v;
        *(s4v*)(orow + 32 + d) = v1.v;
    }
}

extern "C" void kernel_launch(void* const* d_in, const int* in_sizes, int n_in,
                              void* d_out, int out_size, void* d_ws, size_t ws_size,
                              hipStream_t stream) {
    const float* q  = (const float*)d_in[0];
    const float* k  = (const float*)d_in[1];
    const float* v  = (const float*)d_in[2];
    // d_in[3] = mask (causal tril) — implemented structurally
    const float* Wq = (const float*)d_in[4];
    const float* bq = (const float*)d_in[5];
    const float* Wk = (const float*)d_in[6];
    const float* bk = (const float*)d_in[7];
    const float* Wv = (const float*)d_in[8];
    const float* bv = (const float*)d_in[9];
    const float* Wo = (const float*)d_in[10];
    const float* bo = (const float*)d_in[11];
    float* out = (float*)d_out;

    char* ws = (char*)d_ws;
    unsigned short* Wqt = (unsigned short*)(ws + 25165824);  //  2 MiB each, [n][k] bf16
    unsigned short* Wkt = (unsigned short*)(ws + 27262976);
    unsigned short* Wvt = (unsigned short*)(ws + 29360128);
    unsigned short* Wot = (unsigned short*)(ws + 31457280);
    unsigned short* Qh  = (unsigned short*)(ws + 33554432);  // [B,H,S,DK] bf16 (pre-scaled)
    unsigned short* Kh  = (unsigned short*)(ws + 41943040);  // [B,H,S,DK] bf16
    unsigned short* Vtp = (unsigned short*)(ws + 50331648);  // [B,H,DK,S] bf16
    unsigned short* xat = (unsigned short*)(ws + 58720256);  // [4096][1024] bf16

    prep_w<<<dim3(256, 1, 4), 256, 0, stream>>>(Wq, Wk, Wv, Wo, Wqt, Wkt, Wvt, Wot);
    qkv_gemm<<<dim3(256, 1, 3), 256, 0, stream>>>(q, k, v, Wqt, Wkt, Wvt,
                                                  bq, bk, bv, Qh, Kh, Vtp);
    attn_kernel<<<dim3(2048), 256, 0, stream>>>(Qh, Kh, Vtp, xat);
    out_gemm<<<dim3(256), 256, 0, stream>>>(xat, Wot, bo, out);
}

// Round 18
// 133.651 us; speedup vs baseline: 1.3055x; 1.3055x over previous
//
#include <hip/hip_runtime.h>
#include <hip/hip_bf16.h>
#include <stdint.h>

#define Bb 2
#define Ss 2048
#define Dd 1024
#define Hh 16
#define DKk 64

// softmax scale folded into Q at projection time: 1/sqrt(64) * log2(e)
#define QSCALE 0.180336878f

typedef __attribute__((ext_vector_type(8))) short s8v;
typedef __attribute__((ext_vector_type(4))) short s4v;
typedef __attribute__((ext_vector_type(4))) float f4v;
typedef __attribute__((ext_vector_type(16))) float f16v;

#if __has_builtin(__builtin_amdgcn_exp2f)
#define EXP2(x) __builtin_amdgcn_exp2f(x)
#else
#define EXP2(x) __expf((x)*0.69314718f)
#endif

__device__ __forceinline__ unsigned short f2bf(float f) {
    __hip_bfloat16 h = __float2bfloat16(f);
    union { __hip_bfloat16 h; unsigned short u; } c; c.h = h;
    return c.u;
}

__device__ __forceinline__ unsigned pack_bf2(float lo, float hi) {
    __hip_bfloat162 h = __float22bfloat162_rn(float2{lo, hi});
    union { __hip_bfloat162 h; unsigned u; } c; c.h = h;
    return c.u;
}

__device__ __forceinline__ void gload16(const void* g, void* l) {
    __builtin_amdgcn_global_load_lds((__attribute__((address_space(1))) void*)g,
                                     (__attribute__((address_space(3))) void*)l, 16, 0, 0);
}

// ---------------- prep: f32 -> bf16 conversion of q,k,v ----------------
__global__ void __launch_bounds__(256) prep_x(const float* __restrict__ q,
                                              const float* __restrict__ k,
                                              const float* __restrict__ v,
                                              unsigned short* __restrict__ xq,
                                              unsigned short* __restrict__ xk,
                                              unsigned short* __restrict__ xv) {
    const int z = blockIdx.z;
    const float* s = (z == 0) ? q : ((z == 1) ? k : v);
    unsigned short* d = (z == 0) ? xq : ((z == 1) ? xk : xv);
    long i = ((long)blockIdx.x * blockDim.x + threadIdx.x) * 8;
    f4v a = *(const f4v*)(s + i);
    f4v b = *(const f4v*)(s + i + 4);
    union { unsigned u[4]; s8v v; } o;
    o.u[0] = pack_bf2(a[0], a[1]);
    o.u[1] = pack_bf2(a[2], a[3]);
    o.u[2] = pack_bf2(b[0], b[1]);
    o.u[3] = pack_bf2(b[2], b[3]);
    *(s8v*)(void*)(d + i) = o.v;
}

// ---------------- prep: transpose+convert weights to [n][k] bf16 ----------------
__global__ void __launch_bounds__(256) prep_w(const float* __restrict__ Wq,
                                              const float* __restrict__ Wk,
                                              const float* __restrict__ Wv,
                                              const float* __restrict__ Wo,
                                              unsigned short* __restrict__ o0,
                                              unsigned short* __restrict__ o1,
                                              unsigned short* __restrict__ o2,
                                              unsigned short* __restrict__ o3) {
    __shared__ float t[64][65];
    const int z = blockIdx.z;
    const float* W = (z == 0) ? Wq : ((z == 1) ? Wk : ((z == 2) ? Wv : Wo));
    unsigned short* O = (z == 0) ? o0 : ((z == 1) ? o1 : ((z == 2) ? o2 : o3));
    const int n0 = (blockIdx.x & 15) * 64;
    const int k0 = (blockIdx.x >> 4) * 64;
    const int c = threadIdx.x & 63;
    const int r4 = threadIdx.x >> 6;
#pragma unroll
    for (int i = 0; i < 16; i++) {
        int r = i * 4 + r4;
        t[r][c] = W[(long)(k0 + r) * Dd + n0 + c];
    }
    __syncthreads();
#pragma unroll
    for (int i = 0; i < 16; i++) {
        int r = i * 4 + r4;  // n-local
        O[(long)(n0 + r) * Dd + k0 + c] = f2bf(t[c][r]);
    }
}

// ---------------- bf16 GEMM body (R15-validated 2-phase K-loop) ----------------
// MODE 0: write bf16 head-split [B,H,S,DK] (scaled); MODE 1: bf16 [B,H,DK,S]; MODE 2: f32
template <int MODE>
__device__ __forceinline__ void gemm_body(const unsigned short* __restrict__ A,
                                          const unsigned short* __restrict__ Bt,
                                          const float* __restrict__ bias,
                                          void* __restrict__ out, float oscale,
                                          unsigned short* smem, int m0, int n0) {
    unsigned short* As = smem;
    unsigned short* Bs = smem + 128 * 64;
    const int tid = threadIdx.x;
    const int l = tid & 63;
    const int w = tid >> 6;
    const int wr = w >> 1, wc = w & 1;
    const int lr = l & 15, lg = l >> 4;

    f4v acc[4][4];
#pragma unroll
    for (int m = 0; m < 4; m++)
#pragma unroll
        for (int n = 0; n < 4; n++) acc[m][n] = (f4v){0.f, 0.f, 0.f, 0.f};

    const int srow = tid >> 3;              // 0..31 (row within 32-row chunk)
    const int sg = (tid & 7) ^ (srow & 7);  // pre-swizzled source granule (T2 both-sides)
    char* lbaseA = (char*)As + w * 1024;
    char* lbaseB = (char*)Bs + w * 1024;

#define STAGE_T(t_)                                                                    \
    do {                                                                               \
        const int k0_ = (t_) * 64;                                                     \
        _Pragma("unroll") for (int i_ = 0; i_ < 4; i_++) {                             \
            int rowA_ = i_ * 32 + srow;                                                \
            gload16((const char*)A + ((long)(m0 + rowA_) * 1024 + k0_) * 2 + sg * 16,  \
                    lbaseA + i_ * 4096);                                               \
            gload16((const char*)Bt + ((long)(n0 + rowA_) * 1024 + k0_) * 2 + sg * 16, \
                    lbaseB + i_ * 4096);                                               \
        }                                                                              \
    } while (0)

    STAGE_T(0);
    for (int t = 0; t < 16; t++) {
        asm volatile("s_waitcnt vmcnt(0)" ::: "memory");
        __builtin_amdgcn_s_barrier();       // LDS tile t ready (all waves)
        __builtin_amdgcn_sched_barrier(0);

        // read ALL fragments for this tile into registers
        s8v af[2][4], bfr[2][4];
#pragma unroll
        for (int kk = 0; kk < 2; kk++) {
#pragma unroll
            for (int m = 0; m < 4; m++) {
                int row = wr * 64 + m * 16 + lr;
                int gc = (kk * 4 + lg) ^ (row & 7);
                af[kk][m] = *(const s8v*)((const char*)As + row * 128 + gc * 16);
            }
#pragma unroll
            for (int n = 0; n < 4; n++) {
                int row = wc * 64 + n * 16 + lr;
                int gc = (kk * 4 + lg) ^ (row & 7);
                bfr[kk][n] = *(const s8v*)((const char*)Bs + row * 128 + gc * 16);
            }
        }
        asm volatile("s_waitcnt lgkmcnt(0)" ::: "memory");
        __builtin_amdgcn_sched_barrier(0);  // rule #18: fence reads before barrier
        __builtin_amdgcn_s_barrier();       // all waves done reading LDS tile t
        __builtin_amdgcn_sched_barrier(0);

        if (t + 1 < 16) STAGE_T(t + 1);     // async overwrite; hidden under MFMAs

#pragma unroll
        for (int kk = 0; kk < 2; kk++)
#pragma unroll
            for (int m = 0; m < 4; m++)
#pragma unroll
                for (int n = 0; n < 4; n++)
                    acc[m][n] = __builtin_amdgcn_mfma_f32_16x16x32_bf16(
                        af[kk][m], bfr[kk][n], acc[m][n], 0, 0, 0);
    }
#undef STAGE_T

#pragma unroll
    for (int n = 0; n < 4; n++) {
        int col = n0 + wc * 64 + n * 16 + lr;
        float bv = bias[col];
#pragma unroll
        for (int m = 0; m < 4; m++) {
#pragma unroll
            for (int r = 0; r < 4; r++) {
                int row = m0 + wr * 64 + m * 16 + lg * 4 + r;
                float val = acc[m][n][r] + bv;
                if (MODE == 0) {
                    int b = row >> 11, s2 = row & 2047, h = col >> 6, d = col & 63;
                    ((unsigned short*)out)[(((b * Hh + h) * Ss + s2) << 6) + d] =
                        f2bf(val * oscale);
                } else if (MODE == 1) {
                    int b = row >> 11, s2 = row & 2047, h = col >> 6, d = col & 63;
                    ((unsigned short*)out)[((b * Hh + h) * DKk + d) * Ss + s2] = f2bf(val);
                } else {
                    ((float*)out)[(long)row * Dd + col] = val;
                }
            }
        }
    }
}

// T1 bijective XCD swizzle for a 256-block slice (256 % 8 == 0).
__device__ __forceinline__ void xcd_tile(int bid, int& m0, int& n0) {
    int content = (bid & 7) * 32 + (bid >> 3);
    n0 = (content & 7) * 128;
    m0 = (content >> 3) * 128;
}

__global__ void __launch_bounds__(256) qkv_gemm(const unsigned short* __restrict__ xq,
                                                const unsigned short* __restrict__ xk,
                                                const unsigned short* __restrict__ xv,
                                                const unsigned short* __restrict__ Wqt,
                                                const unsigned short* __restrict__ Wkt,
                                                const unsigned short* __restrict__ Wvt,
                                                const float* __restrict__ bq,
                                                const float* __restrict__ bk,
                                                const float* __restrict__ bv,
                                                unsigned short* __restrict__ Qh,
                                                unsigned short* __restrict__ Kh,
                                                unsigned short* __restrict__ Vt) {
    __shared__ unsigned short smem[128 * 64 * 2];
    int m0, n0;
    xcd_tile(blockIdx.x, m0, n0);
    const int z = blockIdx.z;
    if (z == 0)
        gemm_body<0>(xq, Wqt, bq, Qh, QSCALE, smem, m0, n0);
    else if (z == 1)
        gemm_body<0>(xk, Wkt, bk, Kh, 1.f, smem, m0, n0);
    else
        gemm_body<1>(xv, Wvt, bv, Vt, 1.f, smem, m0, n0);
}

__global__ void __launch_bounds__(256) out_gemm(const unsigned short* __restrict__ x,
                                                const unsigned short* __restrict__ Wot,
                                                const float* __restrict__ bo,
                                                float* __restrict__ out) {
    __shared__ unsigned short smem[128 * 64 * 2];
    int m0, n0;
    xcd_tile(blockIdx.x, m0, n0);
    gemm_body<2>(x, Wot, bo, out, 1.f, smem, m0, n0);
}

// ---------------- flash attention: R7 structure + R15's 2-phase chunk loop -------
// Per chunk: vmcnt(0)+barrier (chunk ready) -> ds_read ALL K/V frags to regs
// (unconditional) -> lgkmcnt(0)+sched_barrier+barrier (all waves done reading) ->
// STAGE(ch+1) async into same buffer -> register-only compute (QK^T/softmax/PV).
__global__ void __launch_bounds__(256) attn_kernel(const unsigned short* __restrict__ Qh,
                                                   const unsigned short* __restrict__ Kh,
                                                   const unsigned short* __restrict__ Vt,
                                                   unsigned short* __restrict__ xatt) {
    __shared__ __align__(16) char ldsbuf[32768];
    unsigned short* Ks = (unsigned short*)ldsbuf;            // 16 KB: [128 rows][8 gran]
    unsigned short* Vs = (unsigned short*)(ldsbuf + 16384);  // 16 KB: [64 rows][16 gran]
    const int tid = threadIdx.x;
    const int w = tid >> 6, l = tid & 63;
    const int lq = l & 31;   // operand row index / q column
    const int hi = l >> 5;   // half-lane group
    const int bh = blockIdx.x & 31;          // b*16+h
    const int tile = 63 - (blockIdx.x >> 5); // longest-running tiles dispatch first
    const int q0 = tile * 32;
    const int b = bh >> 4, h = bh & 15;
    const unsigned short* Qp = Qh + bh * Ss * DKk;
    const unsigned short* Kp = Kh + bh * Ss * DKk;
    const unsigned short* Vp = Vt + bh * DKk * Ss;

    // Q as B-operand: row = q (lane&31), k = kk*16 + hi*8 + j
    s8v qf[4];
#pragma unroll
    for (int kk = 0; kk < 4; kk++)
        qf[kk] = *(const s8v*)(Qp + (q0 + lq) * 64 + kk * 16 + hi * 8);

    f16v oT0, oT1;
#pragma unroll
    for (int r = 0; r < 16; r++) { oT0[r] = 0.f; oT1[r] = 0.f; }
    float mx = -1e30f, sm = 0.f;
    const int nkb = tile + 1;          // 32-kv sub-blocks
    const int nch = (nkb + 3) >> 2;    // 128-kv chunks

#define STAGE_CH(ch_)                                                          \
    do {                                                                       \
        const int kv0_ = (ch_) * 128;                                          \
        _Pragma("unroll") for (int i_ = 0; i_ < 4; i_++) {                     \
            const int G0_ = i_ * 256 + w * 64;                                 \
            int G_ = G0_ + l;                                                  \
            int row_ = G_ >> 3, gd_ = G_ & 7;                                  \
            int gs_ = gd_ ^ (row_ & 7);                                        \
            gload16(Kp + (kv0_ + row_) * 64 + gs_ * 8, (char*)Ks + G0_ * 16);  \
        }                                                                      \
        _Pragma("unroll") for (int i_ = 0; i_ < 4; i_++) {                     \
            const int G0_ = i_ * 256 + w * 64;                                 \
            int G_ = G0_ + l;                                                  \
            int row_ = G_ >> 4, gd_ = G_ & 15;                                 \
            int gs_ = gd_ ^ (row_ & 15);                                       \
            gload16(Vp + (long)row_ * Ss + kv0_ + gs_ * 8, (char*)Vs + G0_ * 16); \
        }                                                                      \
    } while (0)

    STAGE_CH(0);
    for (int ch = 0; ch < nch; ch++) {
        asm volatile("s_waitcnt vmcnt(0)" ::: "memory");
        __builtin_amdgcn_s_barrier();       // chunk ch staged (all waves)
        __builtin_amdgcn_sched_barrier(0);

        // read ALL K/V fragments to registers (unconditional; addresses always valid)
        s8v kf[4], vf0[2], vf1[2];
#pragma unroll
        for (int kk = 0; kk < 4; kk++) {
            int row = w * 32 + lq;
            int g = (2 * kk + hi) ^ (row & 7);
            kf[kk] = *(const s8v*)((const char*)Ks + (row * 8 + g) * 16);
        }
#pragma unroll
        for (int kk = 0; kk < 2; kk++) {
            int g0 = 4 * w + 2 * kk + hi;
            vf0[kk] = *(const s8v*)((const char*)Vs + (lq * 16 + (g0 ^ (lq & 15))) * 16);
            vf1[kk] =
                *(const s8v*)((const char*)Vs + ((32 + lq) * 16 + (g0 ^ (lq & 15))) * 16);
        }
        asm volatile("s_waitcnt lgkmcnt(0)" ::: "memory");
        __builtin_amdgcn_sched_barrier(0);  // rule #18: fence reads before barrier
        __builtin_amdgcn_s_barrier();       // all waves done reading chunk ch
        __builtin_amdgcn_sched_barrier(0);

        if (ch + 1 < nch) STAGE_CH(ch + 1); // async overwrite; hidden under compute

        const int kb = ch * 4 + w;  // my 32-kv sub-block
        if (kb < nkb) {
            const int k0 = kb * 32;
            f16v S;
#pragma unroll
            for (int r = 0; r < 16; r++) S[r] = 0.f;
#pragma unroll
            for (int kk = 0; kk < 4; kk++)
                S = __builtin_amdgcn_mfma_f32_32x32x16_bf16(kf[kk], qf[kk], S, 0, 0, 0);

            const bool diag = (kb == nkb - 1);
            float e[16];
#pragma unroll
            for (int r = 0; r < 16; r++) {
                float v = S[r];
                if (diag) {
                    int kv = k0 + (r & 3) + 8 * (r >> 2) + 4 * hi;
                    if (kv > q0 + lq) v = -1e30f;
                }
                e[r] = v;
            }
            // tree max (depth 4) + cross-half via shfl_xor (validated)
            float m8[8];
#pragma unroll
            for (int i = 0; i < 8; i++) m8[i] = fmaxf(e[i], e[i + 8]);
#pragma unroll
            for (int i = 0; i < 4; i++) m8[i] = fmaxf(m8[i], m8[i + 4]);
            float pmax = fmaxf(fmaxf(m8[0], m8[1]), fmaxf(m8[2], m8[3]));
            pmax = fmaxf(pmax, __shfl_xor(pmax, 32));

            if (!__all(pmax - mx <= 8.f)) {
                float mn = fmaxf(mx, pmax);
                float sc = EXP2(mx - mn);
                mx = mn;
                sm *= sc;
#pragma unroll
                for (int r = 0; r < 16; r++) { oT0[r] *= sc; oT1[r] *= sc; }
            }
#pragma unroll
            for (int r = 0; r < 16; r++) e[r] = EXP2(e[r] - mx);
            float s8s[8];
#pragma unroll
            for (int i = 0; i < 8; i++) s8s[i] = e[i] + e[i + 8];
#pragma unroll
            for (int i = 0; i < 4; i++) s8s[i] = s8s[i] + s8s[i + 4];
            float rs = (s8s[0] + s8s[1]) + (s8s[2] + s8s[3]);
            sm += rs + __shfl_xor(rs, 32);

            // pack P to bf16x2 pairs; half-exchange via shfl_xor (R5-validated mapping)
            unsigned pk[8], sw[8];
#pragma unroll
            for (int i = 0; i < 8; i++) pk[i] = pack_bf2(e[2 * i], e[2 * i + 1]);
#pragma unroll
            for (int i = 0; i < 8; i++) sw[i] = (unsigned)__shfl_xor((int)pk[i], 32);
            union { unsigned u[4]; s8v v; } p0, p1;
            p0.u[0] = hi ? sw[2] : pk[0];
            p0.u[1] = hi ? sw[3] : pk[1];
            p0.u[2] = hi ? pk[2] : sw[0];
            p0.u[3] = hi ? pk[3] : sw[1];
            p1.u[0] = hi ? sw[6] : pk[4];
            p1.u[1] = hi ? sw[7] : pk[5];
            p1.u[2] = hi ? pk[6] : sw[4];
            p1.u[3] = hi ? pk[7] : sw[5];

            oT0 = __builtin_amdgcn_mfma_f32_32x32x16_bf16(vf0[0], p0.v, oT0, 0, 0, 0);
            oT0 = __builtin_amdgcn_mfma_f32_32x32x16_bf16(vf0[1], p1.v, oT0, 0, 0, 0);
            oT1 = __builtin_amdgcn_mfma_f32_32x32x16_bf16(vf1[0], p0.v, oT1, 0, 0, 0);
            oT1 = __builtin_amdgcn_mfma_f32_32x32x16_bf16(vf1[1], p1.v, oT1, 0, 0, 0);
        }
    }
#undef STAGE_CH

    // ---- merge the 4 per-wave partials (2-round LDS tree; aliases staging LDS).
    // Safe: final iteration's vmcnt(0) retired all staging; compute is register-only.
    float(*plds)[64][34] = (float(*)[64][34])ldsbuf;
    if (w >= 2) {
        float* p = plds[w - 2][l];
        p[0] = mx; p[1] = sm;
#pragma unroll
        for (int r = 0; r < 16; r++) { p[2 + r] = oT0[r]; p[18 + r] = oT1[r]; }
    }
    __syncthreads();
    if (w < 2) {
        const float* p = plds[w][l];
        float m2 = p[0], s2 = p[1];
        float M = fmaxf(mx, m2);
        float a = EXP2(mx - M), bb = EXP2(m2 - M);
        sm = sm * a + s2 * bb;
#pragma unroll
        for (int r = 0; r < 16; r++) {
            oT0[r] = oT0[r] * a + p[2 + r] * bb;
            oT1[r] = oT1[r] * a + p[18 + r] * bb;
        }
        mx = M;
    }
    __syncthreads();
    if (w == 1) {
        float* p = plds[0][l];
        p[0] = mx; p[1] = sm;
#pragma unroll
        for (int r = 0; r < 16; r++) { p[2 + r] = oT0[r]; p[18 + r] = oT1[r]; }
    }
    __syncthreads();
    if (w != 0) return;
    {
        const float* p = plds[0][l];
        float m2 = p[0], s2 = p[1];
        float M = fmaxf(mx, m2);
        float a = EXP2(mx - M), bb = EXP2(m2 - M);
        sm = sm * a + s2 * bb;
#pragma unroll
        for (int r = 0; r < 16; r++) {
            oT0[r] = oT0[r] * a + p[2 + r] * bb;
            oT1[r] = oT1[r] * a + p[18 + r] * bb;
        }
    }

    // epilogue: O^T col = q (lane-local), row d = (r&3)+8*(r>>2)+4*hi
    const float inv = 1.f / sm;
    const int q = q0 + lq;
    unsigned short* orow = xatt + (long)(b * Ss + q) * Dd + h * 64;
#pragma unroll
    for (int g = 0; g < 4; g++) {
        union { unsigned u[2]; s4v v; } v0, v1;
        v0.u[0] = pack_bf2(oT0[g * 4 + 0] * inv, oT0[g * 4 + 1] * inv);
        v0.u[1] = pack_bf2(oT0[g * 4 + 2] * inv, oT0[g * 4 + 3] * inv);
        v1.u[0] = pack_bf2(oT1[g * 4 + 0] * inv, oT1[g * 4 + 1] * inv);
        v1.u[1] = pack_bf2(oT1[g * 4 + 2] * inv, oT1[g * 4 + 3] * inv);
        int d = 8 * g + 4 * hi;
        *(s4v*)(orow + d) = v0.v;
        *(s4v*)(orow + 32 + d) = v1.v;
    }
}

extern "C" void kernel_launch(void* const* d_in, const int* in_sizes, int n_in,
                              void* d_out, int out_size, void* d_ws, size_t ws_size,
                              hipStream_t stream) {
    const float* q  = (const float*)d_in[0];
    const float* k  = (const float*)d_in[1];
    const float* v  = (const float*)d_in[2];
    // d_in[3] = mask (causal tril) — implemented structurally
    const float* Wq = (const float*)d_in[4];
    const float* bq = (const float*)d_in[5];
    const float* Wk = (const float*)d_in[6];
    const float* bk = (const float*)d_in[7];
    const float* Wv = (const float*)d_in[8];
    const float* bv = (const float*)d_in[9];
    const float* Wo = (const float*)d_in[10];
    const float* bo = (const float*)d_in[11];
    float* out = (float*)d_out;

    char* ws = (char*)d_ws;
    unsigned short* xq  = (unsigned short*)(ws + 0);         //  8 MiB  [4096][1024] bf16
    unsigned short* xk  = (unsigned short*)(ws + 8388608);
    unsigned short* xv  = (unsigned short*)(ws + 16777216);
    unsigned short* Wqt = (unsigned short*)(ws + 25165824);  //  2 MiB each, [n][k] bf16
    unsigned short* Wkt = (unsigned short*)(ws + 27262976);
    unsigned short* Wvt = (unsigned short*)(ws + 29360128);
    unsigned short* Wot = (unsigned short*)(ws + 31457280);
    unsigned short* Qh  = (unsigned short*)(ws + 33554432);  // [B,H,S,DK] bf16 (pre-scaled)
    unsigned short* Kh  = (unsigned short*)(ws + 41943040);  // [B,H,S,DK] bf16
    unsigned short* Vtp = (unsigned short*)(ws + 50331648);  // [B,H,DK,S] bf16
    unsigned short* xat = (unsigned short*)(ws + 58720256);  // [4096][1024] bf16

    prep_x<<<dim3(2048, 1, 3), 256, 0, stream>>>(q, k, v, xq, xk, xv);
    prep_w<<<dim3(256, 1, 4), 256, 0, stream>>>(Wq, Wk, Wv, Wo, Wqt, Wkt, Wvt, Wot);
    qkv_gemm<<<dim3(256, 1, 3), 256, 0, stream>>>(xq, xk, xv, Wqt, Wkt, Wvt,
                                                  bq, bk, bv, Qh, Kh, Vtp);
    attn_kernel<<<dim3(2048), 256, 0, stream>>>(Qh, Kh, Vtp, xat);
    out_gemm<<<dim3(256), 256, 0, stream>>>(xat, Wot, bo, out);
}

// Round 19
// 131.693 us; speedup vs baseline: 1.3250x; 1.0149x over previous
//
#include <hip/hip_runtime.h>
#include <hip/hip_bf16.h>
#include <stdint.h>

#define Bb 2
#define Ss 2048
#define Dd 1024
#define Hh 16
#define DKk 64

// softmax scale folded into Q at projection time: 1/sqrt(64) * log2(e)
#define QSCALE 0.180336878f

typedef __attribute__((ext_vector_type(8))) short s8v;
typedef __attribute__((ext_vector_type(4))) short s4v;
typedef __attribute__((ext_vector_type(4))) float f4v;
typedef __attribute__((ext_vector_type(16))) float f16v;

#if __has_builtin(__builtin_amdgcn_exp2f)
#define EXP2(x) __builtin_amdgcn_exp2f(x)
#else
#define EXP2(x) __expf((x)*0.69314718f)
#endif

__device__ __forceinline__ unsigned short f2bf(float f) {
    __hip_bfloat16 h = __float2bfloat16(f);
    union { __hip_bfloat16 h; unsigned short u; } c; c.h = h;
    return c.u;
}

__device__ __forceinline__ unsigned pack_bf2(float lo, float hi) {
    __hip_bfloat162 h = __float22bfloat162_rn(float2{lo, hi});
    union { __hip_bfloat162 h; unsigned u; } c; c.h = h;
    return c.u;
}

__device__ __forceinline__ void gload16(const void* g, void* l) {
    __builtin_amdgcn_global_load_lds((__attribute__((address_space(1))) void*)g,
                                     (__attribute__((address_space(3))) void*)l, 16, 0, 0);
}

// ---------------- fused prep: x f32->bf16 convert + weight transpose ----------------
// bid < 6144: prep_x body (z = bid>>11, 2048 blocks each for q/k/v).
// bid >= 6144: prep_w body (z = (bid-6144)>>8, 256 blocks each for Wq/Wk/Wv/Wo).
// Whole-block path split (no divergence); bodies byte-identical to validated R18 code.
__global__ void __launch_bounds__(256) prep_all(const float* __restrict__ q,
                                                const float* __restrict__ k,
                                                const float* __restrict__ v,
                                                const float* __restrict__ Wq,
                                                const float* __restrict__ Wk,
                                                const float* __restrict__ Wv,
                                                const float* __restrict__ Wo,
                                                unsigned short* __restrict__ xq,
                                                unsigned short* __restrict__ xk,
                                                unsigned short* __restrict__ xv,
                                                unsigned short* __restrict__ o0,
                                                unsigned short* __restrict__ o1,
                                                unsigned short* __restrict__ o2,
                                                unsigned short* __restrict__ o3) {
    __shared__ float t[64][65];
    const int bid = blockIdx.x;
    if (bid < 6144) {
        const int z = bid >> 11;
        const int xb = bid & 2047;
        const float* s = (z == 0) ? q : ((z == 1) ? k : v);
        unsigned short* d = (z == 0) ? xq : ((z == 1) ? xk : xv);
        long i = ((long)xb * 256 + threadIdx.x) * 8;
        f4v a = *(const f4v*)(s + i);
        f4v b = *(const f4v*)(s + i + 4);
        union { unsigned u[4]; s8v v; } o;
        o.u[0] = pack_bf2(a[0], a[1]);
        o.u[1] = pack_bf2(a[2], a[3]);
        o.u[2] = pack_bf2(b[0], b[1]);
        o.u[3] = pack_bf2(b[2], b[3]);
        *(s8v*)(void*)(d + i) = o.v;
    } else {
        const int idx = bid - 6144;
        const int z = idx >> 8;
        const int xb = idx & 255;
        const float* W = (z == 0) ? Wq : ((z == 1) ? Wk : ((z == 2) ? Wv : Wo));
        unsigned short* O = (z == 0) ? o0 : ((z == 1) ? o1 : ((z == 2) ? o2 : o3));
        const int n0 = (xb & 15) * 64;
        const int k0 = (xb >> 4) * 64;
        const int c = threadIdx.x & 63;
        const int r4 = threadIdx.x >> 6;
#pragma unroll
        for (int i = 0; i < 16; i++) {
            int r = i * 4 + r4;
            t[r][c] = W[(long)(k0 + r) * Dd + n0 + c];
        }
        __syncthreads();
#pragma unroll
        for (int i = 0; i < 16; i++) {
            int r = i * 4 + r4;  // n-local
            O[(long)(n0 + r) * Dd + k0 + c] = f2bf(t[c][r]);
        }
    }
}

// ---------------- bf16 GEMM body (R15-validated 2-phase K-loop) ----------------
// MODE 0: write bf16 head-split [B,H,S,DK] (scaled); MODE 1: bf16 [B,H,DK,S]; MODE 2: f32
template <int MODE>
__device__ __forceinline__ void gemm_body(const unsigned short* __restrict__ A,
                                          const unsigned short* __restrict__ Bt,
                                          const float* __restrict__ bias,
                                          void* __restrict__ out, float oscale,
                                          unsigned short* smem, int m0, int n0) {
    unsigned short* As = smem;
    unsigned short* Bs = smem + 128 * 64;
    const int tid = threadIdx.x;
    const int l = tid & 63;
    const int w = tid >> 6;
    const int wr = w >> 1, wc = w & 1;
    const int lr = l & 15, lg = l >> 4;

    f4v acc[4][4];
#pragma unroll
    for (int m = 0; m < 4; m++)
#pragma unroll
        for (int n = 0; n < 4; n++) acc[m][n] = (f4v){0.f, 0.f, 0.f, 0.f};

    const int srow = tid >> 3;              // 0..31 (row within 32-row chunk)
    const int sg = (tid & 7) ^ (srow & 7);  // pre-swizzled source granule (T2 both-sides)
    char* lbaseA = (char*)As + w * 1024;
    char* lbaseB = (char*)Bs + w * 1024;

#define STAGE_T(t_)                                                                    \
    do {                                                                               \
        const int k0_ = (t_) * 64;                                                     \
        _Pragma("unroll") for (int i_ = 0; i_ < 4; i_++) {                             \
            int rowA_ = i_ * 32 + srow;                                                \
            gload16((const char*)A + ((long)(m0 + rowA_) * 1024 + k0_) * 2 + sg * 16,  \
                    lbaseA + i_ * 4096);                                               \
            gload16((const char*)Bt + ((long)(n0 + rowA_) * 1024 + k0_) * 2 + sg * 16, \
                    lbaseB + i_ * 4096);                                               \
        }                                                                              \
    } while (0)

    STAGE_T(0);
    for (int t = 0; t < 16; t++) {
        asm volatile("s_waitcnt vmcnt(0)" ::: "memory");
        __builtin_amdgcn_s_barrier();       // LDS tile t ready (all waves)
        __builtin_amdgcn_sched_barrier(0);

        // read ALL fragments for this tile into registers
        s8v af[2][4], bfr[2][4];
#pragma unroll
        for (int kk = 0; kk < 2; kk++) {
#pragma unroll
            for (int m = 0; m < 4; m++) {
                int row = wr * 64 + m * 16 + lr;
                int gc = (kk * 4 + lg) ^ (row & 7);
                af[kk][m] = *(const s8v*)((const char*)As + row * 128 + gc * 16);
            }
#pragma unroll
            for (int n = 0; n < 4; n++) {
                int row = wc * 64 + n * 16 + lr;
                int gc = (kk * 4 + lg) ^ (row & 7);
                bfr[kk][n] = *(const s8v*)((const char*)Bs + row * 128 + gc * 16);
            }
        }
        asm volatile("s_waitcnt lgkmcnt(0)" ::: "memory");
        __builtin_amdgcn_sched_barrier(0);  // rule #18: fence reads before barrier
        __builtin_amdgcn_s_barrier();       // all waves done reading LDS tile t
        __builtin_amdgcn_sched_barrier(0);

        if (t + 1 < 16) STAGE_T(t + 1);     // async overwrite; hidden under MFMAs

#pragma unroll
        for (int kk = 0; kk < 2; kk++)
#pragma unroll
            for (int m = 0; m < 4; m++)
#pragma unroll
                for (int n = 0; n < 4; n++)
                    acc[m][n] = __builtin_amdgcn_mfma_f32_16x16x32_bf16(
                        af[kk][m], bfr[kk][n], acc[m][n], 0, 0, 0);
    }
#undef STAGE_T

#pragma unroll
    for (int n = 0; n < 4; n++) {
        int col = n0 + wc * 64 + n * 16 + lr;
        float bv = bias[col];
#pragma unroll
        for (int m = 0; m < 4; m++) {
#pragma unroll
            for (int r = 0; r < 4; r++) {
                int row = m0 + wr * 64 + m * 16 + lg * 4 + r;
                float val = acc[m][n][r] + bv;
                if (MODE == 0) {
                    int b = row >> 11, s2 = row & 2047, h = col >> 6, d = col & 63;
                    ((unsigned short*)out)[(((b * Hh + h) * Ss + s2) << 6) + d] =
                        f2bf(val * oscale);
                } else if (MODE == 1) {
                    int b = row >> 11, s2 = row & 2047, h = col >> 6, d = col & 63;
                    ((unsigned short*)out)[((b * Hh + h) * DKk + d) * Ss + s2] = f2bf(val);
                } else {
                    ((float*)out)[(long)row * Dd + col] = val;
                }
            }
        }
    }
}

// T1 bijective XCD swizzle for a 256-block slice (256 % 8 == 0).
__device__ __forceinline__ void xcd_tile(int bid, int& m0, int& n0) {
    int content = (bid & 7) * 32 + (bid >> 3);
    n0 = (content & 7) * 128;
    m0 = (content >> 3) * 128;
}

__global__ void __launch_bounds__(256) qkv_gemm(const unsigned short* __restrict__ xq,
                                                const unsigned short* __restrict__ xk,
                                                const unsigned short* __restrict__ xv,
                                                const unsigned short* __restrict__ Wqt,
                                                const unsigned short* __restrict__ Wkt,
                                                const unsigned short* __restrict__ Wvt,
                                                const float* __restrict__ bq,
                                                const float* __restrict__ bk,
                                                const float* __restrict__ bv,
                                                unsigned short* __restrict__ Qh,
                                                unsigned short* __restrict__ Kh,
                                                unsigned short* __restrict__ Vt) {
    __shared__ unsigned short smem[128 * 64 * 2];
    int m0, n0;
    xcd_tile(blockIdx.x, m0, n0);
    const int z = blockIdx.z;
    if (z == 0)
        gemm_body<0>(xq, Wqt, bq, Qh, QSCALE, smem, m0, n0);
    else if (z == 1)
        gemm_body<0>(xk, Wkt, bk, Kh, 1.f, smem, m0, n0);
    else
        gemm_body<1>(xv, Wvt, bv, Vt, 1.f, smem, m0, n0);
}

__global__ void __launch_bounds__(256) out_gemm(const unsigned short* __restrict__ x,
                                                const unsigned short* __restrict__ Wot,
                                                const float* __restrict__ bo,
                                                float* __restrict__ out) {
    __shared__ unsigned short smem[128 * 64 * 2];
    int m0, n0;
    xcd_tile(blockIdx.x, m0, n0);
    gemm_body<2>(x, Wot, bo, out, 1.f, smem, m0, n0);
}

// ---------------- flash attention: R7 structure + R15's 2-phase chunk loop -------
__global__ void __launch_bounds__(256) attn_kernel(const unsigned short* __restrict__ Qh,
                                                   const unsigned short* __restrict__ Kh,
                                                   const unsigned short* __restrict__ Vt,
                                                   unsigned short* __restrict__ xatt) {
    __shared__ __align__(16) char ldsbuf[32768];
    unsigned short* Ks = (unsigned short*)ldsbuf;            // 16 KB: [128 rows][8 gran]
    unsigned short* Vs = (unsigned short*)(ldsbuf + 16384);  // 16 KB: [64 rows][16 gran]
    const int tid = threadIdx.x;
    const int w = tid >> 6, l = tid & 63;
    const int lq = l & 31;   // operand row index / q column
    const int hi = l >> 5;   // half-lane group
    const int bh = blockIdx.x & 31;          // b*16+h
    const int tile = 63 - (blockIdx.x >> 5); // longest-running tiles dispatch first
    const int q0 = tile * 32;
    const int b = bh >> 4, h = bh & 15;
    const unsigned short* Qp = Qh + bh * Ss * DKk;
    const unsigned short* Kp = Kh + bh * Ss * DKk;
    const unsigned short* Vp = Vt + bh * DKk * Ss;

    // Q as B-operand: row = q (lane&31), k = kk*16 + hi*8 + j
    s8v qf[4];
#pragma unroll
    for (int kk = 0; kk < 4; kk++)
        qf[kk] = *(const s8v*)(Qp + (q0 + lq) * 64 + kk * 16 + hi * 8);

    f16v oT0, oT1;
#pragma unroll
    for (int r = 0; r < 16; r++) { oT0[r] = 0.f; oT1[r] = 0.f; }
    float mx = -1e30f, sm = 0.f;
    const int nkb = tile + 1;          // 32-kv sub-blocks
    const int nch = (nkb + 3) >> 2;    // 128-kv chunks

#define STAGE_CH(ch_)                                                          \
    do {                                                                       \
        const int kv0_ = (ch_) * 128;                                          \
        _Pragma("unroll") for (int i_ = 0; i_ < 4; i_++) {                     \
            const int G0_ = i_ * 256 + w * 64;                                 \
            int G_ = G0_ + l;                                                  \
            int row_ = G_ >> 3, gd_ = G_ & 7;                                  \
            int gs_ = gd_ ^ (row_ & 7);                                        \
            gload16(Kp + (kv0_ + row_) * 64 + gs_ * 8, (char*)Ks + G0_ * 16);  \
        }                                                                      \
        _Pragma("unroll") for (int i_ = 0; i_ < 4; i_++) {                     \
            const int G0_ = i_ * 256 + w * 64;                                 \
            int G_ = G0_ + l;                                                  \
            int row_ = G_ >> 4, gd_ = G_ & 15;                                 \
            int gs_ = gd_ ^ (row_ & 15);                                       \
            gload16(Vp + (long)row_ * Ss + kv0_ + gs_ * 8, (char*)Vs + G0_ * 16); \
        }                                                                      \
    } while (0)

    STAGE_CH(0);
    for (int ch = 0; ch < nch; ch++) {
        asm volatile("s_waitcnt vmcnt(0)" ::: "memory");
        __builtin_amdgcn_s_barrier();       // chunk ch staged (all waves)
        __builtin_amdgcn_sched_barrier(0);

        // read ALL K/V fragments to registers (unconditional; addresses always valid)
        s8v kf[4], vf0[2], vf1[2];
#pragma unroll
        for (int kk = 0; kk < 4; kk++) {
            int row = w * 32 + lq;
            int g = (2 * kk + hi) ^ (row & 7);
            kf[kk] = *(const s8v*)((const char*)Ks + (row * 8 + g) * 16);
        }
#pragma unroll
        for (int kk = 0; kk < 2; kk++) {
            int g0 = 4 * w + 2 * kk + hi;
            vf0[kk] = *(const s8v*)((const char*)Vs + (lq * 16 + (g0 ^ (lq & 15))) * 16);
            vf1[kk] =
                *(const s8v*)((const char*)Vs + ((32 + lq) * 16 + (g0 ^ (lq & 15))) * 16);
        }
        asm volatile("s_waitcnt lgkmcnt(0)" ::: "memory");
        __builtin_amdgcn_sched_barrier(0);  // rule #18: fence reads before barrier
        __builtin_amdgcn_s_barrier();       // all waves done reading chunk ch
        __builtin_amdgcn_sched_barrier(0);

        if (ch + 1 < nch) STAGE_CH(ch + 1); // async overwrite; hidden under compute

        const int kb = ch * 4 + w;  // my 32-kv sub-block
        if (kb < nkb) {
            const int k0 = kb * 32;
            f16v S;
#pragma unroll
            for (int r = 0; r < 16; r++) S[r] = 0.f;
#pragma unroll
            for (int kk = 0; kk < 4; kk++)
                S = __builtin_amdgcn_mfma_f32_32x32x16_bf16(kf[kk], qf[kk], S, 0, 0, 0);

            const bool diag = (kb == nkb - 1);
            float e[16];
#pragma unroll
            for (int r = 0; r < 16; r++) {
                float v = S[r];
                if (diag) {
                    int kv = k0 + (r & 3) + 8 * (r >> 2) + 4 * hi;
                    if (kv > q0 + lq) v = -1e30f;
                }
                e[r] = v;
            }
            // tree max (depth 4) + cross-half via shfl_xor (validated)
            float m8[8];
#pragma unroll
            for (int i = 0; i < 8; i++) m8[i] = fmaxf(e[i], e[i + 8]);
#pragma unroll
            for (int i = 0; i < 4; i++) m8[i] = fmaxf(m8[i], m8[i + 4]);
            float pmax = fmaxf(fmaxf(m8[0], m8[1]), fmaxf(m8[2], m8[3]));
            pmax = fmaxf(pmax, __shfl_xor(pmax, 32));

            if (!__all(pmax - mx <= 8.f)) {
                float mn = fmaxf(mx, pmax);
                float sc = EXP2(mx - mn);
                mx = mn;
                sm *= sc;
#pragma unroll
                for (int r = 0; r < 16; r++) { oT0[r] *= sc; oT1[r] *= sc; }
            }
#pragma unroll
            for (int r = 0; r < 16; r++) e[r] = EXP2(e[r] - mx);
            float s8s[8];
#pragma unroll
            for (int i = 0; i < 8; i++) s8s[i] = e[i] + e[i + 8];
#pragma unroll
            for (int i = 0; i < 4; i++) s8s[i] = s8s[i] + s8s[i + 4];
            float rs = (s8s[0] + s8s[1]) + (s8s[2] + s8s[3]);
            sm += rs + __shfl_xor(rs, 32);

            // pack P to bf16x2 pairs; half-exchange via shfl_xor (R5-validated mapping)
            unsigned pk[8], sw[8];
#pragma unroll
            for (int i = 0; i < 8; i++) pk[i] = pack_bf2(e[2 * i], e[2 * i + 1]);
#pragma unroll
            for (int i = 0; i < 8; i++) sw[i] = (unsigned)__shfl_xor((int)pk[i], 32);
            union { unsigned u[4]; s8v v; } p0, p1;
            p0.u[0] = hi ? sw[2] : pk[0];
            p0.u[1] = hi ? sw[3] : pk[1];
            p0.u[2] = hi ? pk[2] : sw[0];
            p0.u[3] = hi ? pk[3] : sw[1];
            p1.u[0] = hi ? sw[6] : pk[4];
            p1.u[1] = hi ? sw[7] : pk[5];
            p1.u[2] = hi ? pk[6] : sw[4];
            p1.u[3] = hi ? pk[7] : sw[5];

            oT0 = __builtin_amdgcn_mfma_f32_32x32x16_bf16(vf0[0], p0.v, oT0, 0, 0, 0);
            oT0 = __builtin_amdgcn_mfma_f32_32x32x16_bf16(vf0[1], p1.v, oT0, 0, 0, 0);
            oT1 = __builtin_amdgcn_mfma_f32_32x32x16_bf16(vf1[0], p0.v, oT1, 0, 0, 0);
            oT1 = __builtin_amdgcn_mfma_f32_32x32x16_bf16(vf1[1], p1.v, oT1, 0, 0, 0);
        }
    }
#undef STAGE_CH

    // ---- merge the 4 per-wave partials (2-round LDS tree; aliases staging LDS).
    // Safe: final iteration's vmcnt(0) retired all staging; compute is register-only.
    float(*plds)[64][34] = (float(*)[64][34])ldsbuf;
    if (w >= 2) {
        float* p = plds[w - 2][l];
        p[0] = mx; p[1] = sm;
#pragma unroll
        for (int r = 0; r < 16; r++) { p[2 + r] = oT0[r]; p[18 + r] = oT1[r]; }
    }
    __syncthreads();
    if (w < 2) {
        const float* p = plds[w][l];
        float m2 = p[0], s2 = p[1];
        float M = fmaxf(mx, m2);
        float a = EXP2(mx - M), bb = EXP2(m2 - M);
        sm = sm * a + s2 * bb;
#pragma unroll
        for (int r = 0; r < 16; r++) {
            oT0[r] = oT0[r] * a + p[2 + r] * bb;
            oT1[r] = oT1[r] * a + p[18 + r] * bb;
        }
        mx = M;
    }
    __syncthreads();
    if (w == 1) {
        float* p = plds[0][l];
        p[0] = mx; p[1] = sm;
#pragma unroll
        for (int r = 0; r < 16; r++) { p[2 + r] = oT0[r]; p[18 + r] = oT1[r]; }
    }
    __syncthreads();
    if (w != 0) return;
    {
        const float* p = plds[0][l];
        float m2 = p[0], s2 = p[1];
        float M = fmaxf(mx, m2);
        float a = EXP2(mx - M), bb = EXP2(m2 - M);
        sm = sm * a + s2 * bb;
#pragma unroll
        for (int r = 0; r < 16; r++) {
            oT0[r] = oT0[r] * a + p[2 + r] * bb;
            oT1[r] = oT1[r] * a + p[18 + r] * bb;
        }
    }

    // epilogue: O^T col = q (lane-local), row d = (r&3)+8*(r>>2)+4*hi
    const float inv = 1.f / sm;
    const int q = q0 + lq;
    unsigned short* orow = xatt + (long)(b * Ss + q) * Dd + h * 64;
#pragma unroll
    for (int g = 0; g < 4; g++) {
        union { unsigned u[2]; s4v v; } v0, v1;
        v0.u[0] = pack_bf2(oT0[g * 4 + 0] * inv, oT0[g * 4 + 1] * inv);
        v0.u[1] = pack_bf2(oT0[g * 4 + 2] * inv, oT0[g * 4 + 3] * inv);
        v1.u[0] = pack_bf2(oT1[g * 4 + 0] * inv, oT1[g * 4 + 1] * inv);
        v1.u[1] = pack_bf2(oT1[g * 4 + 2] * inv, oT1[g * 4 + 3] * inv);
        int d = 8 * g + 4 * hi;
        *(s4v*)(orow + d) = v0.v;
        *(s4v*)(orow + 32 + d) = v1.v;
    }
}

extern "C" void kernel_launch(void* const* d_in, const int* in_sizes, int n_in,
                              void* d_out, int out_size, void* d_ws, size_t ws_size,
                              hipStream_t stream) {
    const float* q  = (const float*)d_in[0];
    const float* k  = (const float*)d_in[1];
    const float* v  = (const float*)d_in[2];
    // d_in[3] = mask (causal tril) — implemented structurally
    const float* Wq = (const float*)d_in[4];
    const float* bq = (const float*)d_in[5];
    const float* Wk = (const float*)d_in[6];
    const float* bk = (const float*)d_in[7];
    const float* Wv = (const float*)d_in[8];
    const float* bv = (const float*)d_in[9];
    const float* Wo = (const float*)d_in[10];
    const float* bo = (const float*)d_in[11];
    float* out = (float*)d_out;

    char* ws = (char*)d_ws;
    unsigned short* xq  = (unsigned short*)(ws + 0);         //  8 MiB  [4096][1024] bf16
    unsigned short* xk  = (unsigned short*)(ws + 8388608);
    unsigned short* xv  = (unsigned short*)(ws + 16777216);
    unsigned short* Wqt = (unsigned short*)(ws + 25165824);  //  2 MiB each, [n][k] bf16
    unsigned short* Wkt = (unsigned short*)(ws + 27262976);
    unsigned short* Wvt = (unsigned short*)(ws + 29360128);
    unsigned short* Wot = (unsigned short*)(ws + 31457280);
    unsigned short* Qh  = (unsigned short*)(ws + 33554432);  // [B,H,S,DK] bf16 (pre-scaled)
    unsigned short* Kh  = (unsigned short*)(ws + 41943040);  // [B,H,S,DK] bf16
    unsigned short* Vtp = (unsigned short*)(ws + 50331648);  // [B,H,DK,S] bf16
    unsigned short* xat = (unsigned short*)(ws + 58720256);  // [4096][1024] bf16

    prep_all<<<dim3(7168), 256, 0, stream>>>(q, k, v, Wq, Wk, Wv, Wo,
                                             xq, xk, xv, Wqt, Wkt, Wvt, Wot);
    qkv_gemm<<<dim3(256, 1, 3), 256, 0, stream>>>(xq, xk, xv, Wqt, Wkt, Wvt,
                                                  bq, bk, bv, Qh, Kh, Vtp);
    attn_kernel<<<dim3(2048), 256, 0, stream>>>(Qh, Kh, Vtp, xat);
    out_gemm<<<dim3(256), 256, 0, stream>>>(xat, Wot, bo, out);
}